// Round 3
// baseline (262.511 us; speedup 1.0000x reference)
//
#include <hip/hip_runtime.h>

#define N_NODES 50000
#define N_EDGES 800000
#define BUCKETS 196   // ceil(N_NODES / 256)
#define ECHUNK 4096
#define EBLKS 196     // ceil(N_EDGES / ECHUNK)
#define BCAP 5120     // bucket capacity; mean 4096, sigma 64 -> 16 sigma headroom

typedef __attribute__((ext_vector_type(8))) _Float16 half8;
typedef __attribute__((ext_vector_type(4))) _Float16 half4;
typedef __attribute__((ext_vector_type(4))) float f32x4;

template <int E> struct hvec;
template <> struct hvec<8> { typedef half8 t; };
template <> struct hvec<4> { typedef half4 t; };

// ---------------- pipelined deep gather-sum ----------------
// L lanes per node, E fp16 elems per lane. DEPTH gathers in flight per round;
// next round's csr indices prefetched while current gathers are outstanding.
// Tail edges clamp to index d-1 (dup gathers are cache hits) and are corrected
// with one fused subtract. Sum order identical to a serial edge loop.

template <int L, int E, int DEPTH>
__device__ __forceinline__ void gather_sum(const _Float16* __restrict__ feat,
                                           const unsigned short* __restrict__ csr,
                                           int start, int d, int lane,
                                           float* acc) {
  using V = typename hvec<E>::t;
  const V* ip = (const V*)feat;
  if (d <= 0) return;
  int nb = (d + DEPTH - 1) / DEPTH;
  int sc[DEPTH];
#pragma unroll
  for (int j = 0; j < DEPTH; ++j) sc[j] = csr[start + (j < d ? j : d - 1)];
  V vlast;
  for (int b = 0; b < nb; ++b) {
    V v[DEPTH];
#pragma unroll
    for (int j = 0; j < DEPTH; ++j) v[j] = ip[(size_t)sc[j] * L + lane];
    int e2 = (b + 1) * DEPTH;
    if (e2 < d) {
#pragma unroll
      for (int j = 0; j < DEPTH; ++j) {
        int idx = e2 + j;
        sc[j] = csr[start + (idx < d ? idx : d - 1)];
      }
    }
#pragma unroll
    for (int j = 0; j < DEPTH; ++j)
#pragma unroll
      for (int q = 0; q < E; ++q) acc[q] += (float)v[j][q];
    vlast = v[DEPTH - 1];
  }
  int rem = d - (nb - 1) * DEPTH;
  if (rem < DEPTH) {
    float corr = (float)(DEPTH - rem);
#pragma unroll
    for (int q = 0; q < E; ++q) acc[q] -= corr * (float)vlast[q];
  }
}

// ---------------- fused prep: binscatter (196) + wprep (32) + xcast (3125) ----------------
// xcast now writes x in SLICED fp16 layout: xh[s][node][32] for s=0..3, so each
// 3.2 MB feature slice is L2-resident on the XCD that aggregates it.

__global__ __launch_bounds__(256) void prep_k(
    const int* __restrict__ src, const int* __restrict__ dst,
    int* __restrict__ gcur, unsigned* __restrict__ binned,
    const float* __restrict__ x, _Float16* __restrict__ xh,
    const float* __restrict__ Wl1, const float* __restrict__ Wr1,
    const float* __restrict__ Wl2, const float* __restrict__ Wr2,
    const float* __restrict__ Wl3, const float* __restrict__ Wr3,
    _Float16* ph_l1, _Float16* pl_l1, _Float16* ph_r1, _Float16* pl_r1,
    _Float16* ph_c2, _Float16* pl_c2, _Float16* ph_l3, _Float16* pl_l3,
    _Float16* ph_r3, _Float16* pl_r3) {
  int blk = blockIdx.x;
  int t = threadIdx.x;
  if (blk < EBLKS) {
    __shared__ int h[BUCKETS];
    __shared__ int base[BUCKETS];
    for (int i = t; i < BUCKETS; i += 256) h[i] = 0;
    __syncthreads();
    int e0 = blk * ECHUNK;
    int eend = e0 + ECHUNK < N_EDGES ? e0 + ECHUNK : N_EDGES;
    for (int e = e0 + t; e < eend; e += 256) atomicAdd(&h[dst[e] >> 8], 1);
    __syncthreads();
    for (int i = t; i < BUCKETS; i += 256) {
      if (h[i]) base[i] = atomicAdd(&gcur[i], h[i]);
      h[i] = 0;  // reuse as local rank cursor
    }
    __syncthreads();
    for (int e = e0 + t; e < eend; e += 256) {
      int d = dst[e];
      int b = d >> 8;
      int r = atomicAdd(&h[b], 1);
      binned[(size_t)b * BCAP + base[b] + r] =
          (unsigned)src[e] | ((unsigned)(d & 255) << 16);
    }
  } else if (blk < EBLKS + 32) {
    // wprep: ph[((kb*128 + n)*4 + lq)*8 + j] = W[n][kb*32 + lq*8 + j]
    int g = (blk - EBLKS) * 256 + t;  // 0..8191
    const float *S0, *S1 = nullptr;
    _Float16 *ph, *pl;
    int f, K;
    if (g < 2048)      { f = g;        ph = ph_l1; pl = pl_l1; S0 = Wl1; K = 128; }
    else if (g < 4096) { f = g - 2048; ph = ph_r1; pl = pl_r1; S0 = Wr1; K = 128; }
    else if (g < 6144) { f = g - 4096; ph = ph_c2; pl = pl_c2; S0 = Wl2; S1 = Wr2; K = 128; }
    else if (g < 7168) { f = g - 6144; ph = ph_l3; pl = pl_l3; S0 = Wl3; K = 64; }
    else               { f = g - 7168; ph = ph_r3; pl = pl_r3; S0 = Wr3; K = 64; }
    int kb = f >> 9;
    int rem = f & 511;
    int n = rem >> 2;
    int lq = rem & 3;
    const float* srow =
        (S1 && n >= 64) ? (S1 + (size_t)(n - 64) * K) : (S0 + (size_t)n * K);
    int kbase = kb * 32 + lq * 8;
#pragma unroll
    for (int j = 0; j < 8; ++j) {
      float v = srow[kbase + j];
      _Float16 hi = (_Float16)v;
      ph[f * 8 + j] = hi;
      pl[f * 8 + j] = (_Float16)(v - (float)hi);
    }
  } else {
    int i = (blk - EBLKS - 32) * 256 + t;  // half8 group, 800000 total
    if (i >= N_NODES * 16) return;
    const float4* xp = (const float4*)x;
    float4 a = xp[2 * i];
    float4 b = xp[2 * i + 1];
    half8 hh;
    hh[0] = (_Float16)a.x; hh[1] = (_Float16)a.y; hh[2] = (_Float16)a.z; hh[3] = (_Float16)a.w;
    hh[4] = (_Float16)b.x; hh[5] = (_Float16)b.y; hh[6] = (_Float16)b.z; hh[7] = (_Float16)b.w;
    int node = i >> 4;
    int part = i & 15;                  // 8-feat group within the 128-feat row
    // sliced: slice s = part/4 holds feats [s*32, s*32+32)
    ((half8*)xh)[(size_t)(part >> 2) * (N_NODES * 4) + (size_t)node * 4 + (part & 3)] = hh;
  }
}

// One block per bucket: per-node offs/deg, node-grouped ushort csr; L2-local writes.
__global__ __launch_bounds__(256) void bucket_fill_k(const unsigned* __restrict__ binned,
                                                     const int* __restrict__ gcnt,
                                                     int* __restrict__ offs,
                                                     int* __restrict__ deg,
                                                     unsigned short* __restrict__ csr) {
  __shared__ int cnt[256];
  __shared__ int loc[256];
  __shared__ int cur[256];
  int b = blockIdx.x;
  int t = threadIdx.x;
  int base = b * BCAP;
  int end = base + gcnt[b];
  cnt[t] = 0;
  __syncthreads();
  for (int e = base + t; e < end; e += 256) atomicAdd(&cnt[(binned[e] >> 16) & 255], 1);
  __syncthreads();
  loc[t] = cnt[t];
  __syncthreads();
  for (int o = 1; o < 256; o <<= 1) {
    int v = (t >= o) ? loc[t - o] : 0;
    __syncthreads();
    loc[t] += v;
    __syncthreads();
  }
  int excl = loc[t] - cnt[t];
  int node = b * 256 + t;
  if (node < N_NODES) {
    offs[node] = base + excl;
    deg[node] = cnt[t];
  }
  cur[t] = excl;
  __syncthreads();
  for (int e = base + t; e < end; e += 256) {
    unsigned r = binned[e];
    int dl = (r >> 16) & 255;
    int p = atomicAdd(&cur[dl], 1);
    csr[base + p] = (unsigned short)(r & 0xFFFF);
  }
}

// ---------------- XCD-local sliced mean aggregation ----------------
// in_sl: NSL slices of [N_NODES][32] fp16 (3.2 MB each -> fits one XCD L2).
// Block -> XCD via blockIdx%8 round-robin; slice s = (blockIdx%8) % NSL, so
// each XCD gathers only from its own L2-resident slice. 32 nodes/block,
// 8 lanes/node, 64 B granule per edge.

template <int NSL, bool FUSE, bool OUTSL>
__global__ __launch_bounds__(256, 4) void agg_sliced_k(
    const _Float16* __restrict__ in_sl, _Float16* __restrict__ out,
    const int* __restrict__ offs, const int* __restrict__ deg,
    const unsigned short* __restrict__ csr, const float* __restrict__ bias,
    const _Float16* __restrict__ addend) {
  constexpr int COPIES = 8 / NSL;   // XCD groups sharing a slice
  constexpr int F = NSL * 32;       // full feature width
  int g = blockIdx.x & 7;
  int s = g % NSL;
  int chunk = (blockIdx.x >> 3) * COPIES + g / NSL;
  int t = threadIdx.x;
  int node = chunk * 32 + (t >> 3);
  int lane = t & 7;
  if (node >= N_NODES) return;
  const _Float16* base = in_sl + (size_t)s * (N_NODES * 32);
  float acc[4] = {0.f, 0.f, 0.f, 0.f};
  int start = offs[node];
  int d = deg[node];
  gather_sum<8, 4, 16>(base, csr, start, d, lane, acc);
  float inv = d > 0 ? 1.0f / (float)d : 0.0f;
  int feat = s * 32 + lane * 4;
  half4 o;
  if constexpr (FUSE) {
    half4 av = *(const half4*)(addend + (size_t)node * F + feat);
#pragma unroll
    for (int q = 0; q < 4; ++q)
      o[q] = (_Float16)(acc[q] * inv + bias[feat + q] + (float)av[q]);
  } else {
#pragma unroll
    for (int q = 0; q < 4; ++q) o[q] = (_Float16)(acc[q] * inv);
  }
  _Float16* op = OUTSL ? out + (size_t)s * (N_NODES * 32) + (size_t)node * 32 + lane * 4
                       : out + (size_t)node * F + feat;
  *(half4*)op = o;
}

// ---------------- megagemm: layer-1 dual GEMM + layer-2 GEMM fused ----------------
// Per block: one 16-row tile. h1 = mean1@Wl1 + x@Wr1 + b1 (fp16, staged in LDS),
// then [P|R] = h1 @ [Wl2;Wr2]. P written sliced (for agg2's XCD-local gather),
// R row-major. Eliminates the 25.6 MB h1 global round-trip.

__global__ __launch_bounds__(256, 4) void megagemm_k(
    const _Float16* __restrict__ mh1, const _Float16* __restrict__ xsl,
    const _Float16* __restrict__ Wl1h, const _Float16* __restrict__ Wl1l,
    const _Float16* __restrict__ Wr1h, const _Float16* __restrict__ Wr1l,
    const float* __restrict__ b1,
    const _Float16* __restrict__ Wc2h, const _Float16* __restrict__ Wc2l,
    _Float16* __restrict__ Psl, _Float16* __restrict__ Rh) {
  constexpr int STR = 136;  // 128 + 8 pad
  __shared__ _Float16 Hsm[16 * STR];
  int t = threadIdx.x;
  int wave = t >> 6;
  int lane = t & 63;
  int l15 = lane & 15;
  int lq = lane >> 4;
  int row0 = blockIdx.x * 16;   // 3125*16 == 50000, no guard needed
  const int woff = (l15 * 4 + lq) * 8;
  int colbase = wave * 32;
  f32x4 acc[2];
  acc[0] = (f32x4){0.f, 0.f, 0.f, 0.f};
  acc[1] = (f32x4){0.f, 0.f, 0.f, 0.f};
  {  // op0: A = mean rows (row-major)
    const _Float16* ab = mh1 + (size_t)(row0 + l15) * 128 + lq * 8;
    half8 af[4];
#pragma unroll
    for (int kb = 0; kb < 4; ++kb) af[kb] = *(const half8*)(ab + kb * 32);
#pragma unroll
    for (int kb = 0; kb < 4; ++kb)
#pragma unroll
      for (int ct = 0; ct < 2; ++ct) {
        size_t bi = (size_t)(kb * 128 + colbase + ct * 16) * 32 + woff;
        half8 bh = *(const half8*)(Wl1h + bi);
        half8 bl = *(const half8*)(Wl1l + bi);
        acc[ct] = __builtin_amdgcn_mfma_f32_16x16x32_f16(af[kb], bh, acc[ct], 0, 0, 0);
        acc[ct] = __builtin_amdgcn_mfma_f32_16x16x32_f16(af[kb], bl, acc[ct], 0, 0, 0);
      }
  }
  {  // op1: A = residual rows from sliced x (slice kb holds feats kb*32..)
    half8 af[4];
#pragma unroll
    for (int kb = 0; kb < 4; ++kb)
      af[kb] = *(const half8*)(xsl + (size_t)kb * (N_NODES * 32) +
                               (size_t)(row0 + l15) * 32 + lq * 8);
#pragma unroll
    for (int kb = 0; kb < 4; ++kb)
#pragma unroll
      for (int ct = 0; ct < 2; ++ct) {
        size_t bi = (size_t)(kb * 128 + colbase + ct * 16) * 32 + woff;
        half8 bh = *(const half8*)(Wr1h + bi);
        half8 bl = *(const half8*)(Wr1l + bi);
        acc[ct] = __builtin_amdgcn_mfma_f32_16x16x32_f16(af[kb], bh, acc[ct], 0, 0, 0);
        acc[ct] = __builtin_amdgcn_mfma_f32_16x16x32_f16(af[kb], bl, acc[ct], 0, 0, 0);
      }
  }
  // stage h1 tile (fp16, +bias) in LDS
#pragma unroll
  for (int r = 0; r < 4; ++r) {
    int rl = lq * 4 + r;
#pragma unroll
    for (int ct = 0; ct < 2; ++ct) {
      int col = colbase + ct * 16 + l15;
      Hsm[rl * STR + col] = (_Float16)(acc[ct][r] + b1[col]);
    }
  }
  __syncthreads();
  // phase B: [P|R] = h1 @ [Wl2;Wr2]^T
  f32x4 a2[2];
  a2[0] = (f32x4){0.f, 0.f, 0.f, 0.f};
  a2[1] = (f32x4){0.f, 0.f, 0.f, 0.f};
  half8 af[4];
#pragma unroll
  for (int kb = 0; kb < 4; ++kb)
    af[kb] = *(const half8*)&Hsm[l15 * STR + kb * 32 + lq * 8];
#pragma unroll
  for (int kb = 0; kb < 4; ++kb)
#pragma unroll
    for (int ct = 0; ct < 2; ++ct) {
      size_t bi = (size_t)(kb * 128 + colbase + ct * 16) * 32 + woff;
      half8 bh = *(const half8*)(Wc2h + bi);
      half8 bl = *(const half8*)(Wc2l + bi);
      a2[ct] = __builtin_amdgcn_mfma_f32_16x16x32_f16(af[kb], bh, a2[ct], 0, 0, 0);
      a2[ct] = __builtin_amdgcn_mfma_f32_16x16x32_f16(af[kb], bl, a2[ct], 0, 0, 0);
    }
#pragma unroll
  for (int r = 0; r < 4; ++r) {
    int row = row0 + lq * 4 + r;
#pragma unroll
    for (int ct = 0; ct < 2; ++ct) {
      int col = colbase + ct * 16 + l15;
      float v = a2[ct][r];
      if (col < 64)  // P -> sliced layout
        Psl[(size_t)(col >> 5) * (N_NODES * 32) + (size_t)row * 32 + (col & 31)] =
            (_Float16)v;
      else           // R -> row-major
        Rh[(size_t)row * 64 + (col - 64)] = (_Float16)v;
    }
  }
}

// ---------------- layer-3 dual GEMM (fp32 out) ----------------

__global__ __launch_bounds__(256, 2) void gemm3_k(
    const _Float16* __restrict__ mh3, const _Float16* __restrict__ h2sl,
    const _Float16* __restrict__ Wlh, const _Float16* __restrict__ Wll,
    const _Float16* __restrict__ Wrh, const _Float16* __restrict__ Wrl,
    const float* __restrict__ b3, float* __restrict__ out) {
  int wave = threadIdx.x >> 6;
  int lane = threadIdx.x & 63;
  int l15 = lane & 15;
  int lq = lane >> 4;
  int rowblk = blockIdx.x >> 1;
  int colg = blockIdx.x & 1;
  int rg = rowblk * 4 + wave;
  if (rg >= N_NODES / 16) return;
  int row0 = rg << 4;
  const int woff = (l15 * 4 + lq) * 8;
  f32x4 acc[4];
#pragma unroll
  for (int c = 0; c < 4; ++c) acc[c] = (f32x4){0.f, 0.f, 0.f, 0.f};
  {  // op0: A = mean3 rows (row-major, K=64)
    const _Float16* ab = mh3 + (size_t)(row0 + l15) * 64 + lq * 8;
    half8 af[2];
#pragma unroll
    for (int kb = 0; kb < 2; ++kb) af[kb] = *(const half8*)(ab + kb * 32);
#pragma unroll
    for (int kb = 0; kb < 2; ++kb)
#pragma unroll
      for (int ct = 0; ct < 4; ++ct) {
        size_t bi = (size_t)(kb * 128 + colg * 64 + ct * 16) * 32 + woff;
        half8 bh = *(const half8*)(Wlh + bi);
        half8 bl = *(const half8*)(Wll + bi);
        acc[ct] = __builtin_amdgcn_mfma_f32_16x16x32_f16(af[kb], bh, acc[ct], 0, 0, 0);
        acc[ct] = __builtin_amdgcn_mfma_f32_16x16x32_f16(af[kb], bl, acc[ct], 0, 0, 0);
      }
  }
  {  // op1: A = residual h2 rows from sliced layout
    half8 af[2];
#pragma unroll
    for (int kb = 0; kb < 2; ++kb)
      af[kb] = *(const half8*)(h2sl + (size_t)kb * (N_NODES * 32) +
                               (size_t)(row0 + l15) * 32 + lq * 8);
#pragma unroll
    for (int kb = 0; kb < 2; ++kb)
#pragma unroll
      for (int ct = 0; ct < 4; ++ct) {
        size_t bi = (size_t)(kb * 128 + colg * 64 + ct * 16) * 32 + woff;
        half8 bh = *(const half8*)(Wrh + bi);
        half8 bl = *(const half8*)(Wrl + bi);
        acc[ct] = __builtin_amdgcn_mfma_f32_16x16x32_f16(af[kb], bh, acc[ct], 0, 0, 0);
        acc[ct] = __builtin_amdgcn_mfma_f32_16x16x32_f16(af[kb], bl, acc[ct], 0, 0, 0);
      }
  }
#pragma unroll
  for (int r = 0; r < 4; ++r) {
    int row = row0 + lq * 4 + r;
#pragma unroll
    for (int ct = 0; ct < 4; ++ct) {
      int col = colg * 64 + ct * 16 + l15;
      out[(size_t)row * 128 + col] = acc[ct][r] + b3[col];
    }
  }
}

extern "C" void kernel_launch(void* const* d_in, const int* in_sizes, int n_in,
                              void* d_out, int out_size, void* d_ws, size_t ws_size,
                              hipStream_t stream) {
  const float* x   = (const float*)d_in[0];
  const int* ei    = (const int*)d_in[1];
  const float* Wl1 = (const float*)d_in[2];
  const float* b1  = (const float*)d_in[3];
  const float* Wr1 = (const float*)d_in[4];
  const float* Wl2 = (const float*)d_in[5];
  const float* b2  = (const float*)d_in[6];
  const float* Wr2 = (const float*)d_in[7];
  const float* Wl3 = (const float*)d_in[8];
  const float* b3  = (const float*)d_in[9];
  const float* Wr3 = (const float*)d_in[10];
  float* out = (float*)d_out;

  const int* src = ei;            // edge_index[0]
  const int* dst = ei + N_EDGES;  // edge_index[1]

  char* ws = (char*)d_ws;
  size_t off = 0;
  auto take = [&](size_t bytes) {
    void* p = ws + off;
    off += (bytes + 255) & ~(size_t)255;
    return p;
  };
  int* deg    = (int*)take((size_t)N_NODES * 4);
  int* offs   = (int*)take((size_t)N_NODES * 4);
  int* gcur   = (int*)take((size_t)BUCKETS * 4);
  unsigned* binned = (unsigned*)take((size_t)BUCKETS * BCAP * 4);
  unsigned short* csr = (unsigned short*)take((size_t)BUCKETS * BCAP * 2);
  _Float16* xh   = (_Float16*)take((size_t)N_NODES * 128 * 2);  // sliced (4x32)
  _Float16* mh1  = (_Float16*)take((size_t)N_NODES * 128 * 2);  // mean1 row-major
  _Float16* Psl  = (_Float16*)take((size_t)N_NODES * 64 * 2);   // sliced (2x32)
  _Float16* Rh   = (_Float16*)take((size_t)N_NODES * 64 * 2);   // row-major
  _Float16* h2sl = (_Float16*)take((size_t)N_NODES * 64 * 2);   // sliced (2x32)
  _Float16* mh3  = (_Float16*)take((size_t)N_NODES * 64 * 2);   // mean3 row-major
  _Float16* ph_l1 = (_Float16*)take(16384 * 2);
  _Float16* pl_l1 = (_Float16*)take(16384 * 2);
  _Float16* ph_r1 = (_Float16*)take(16384 * 2);
  _Float16* pl_r1 = (_Float16*)take(16384 * 2);
  _Float16* ph_c2 = (_Float16*)take(16384 * 2);
  _Float16* pl_c2 = (_Float16*)take(16384 * 2);
  _Float16* ph_l3 = (_Float16*)take(8192 * 2);
  _Float16* pl_l3 = (_Float16*)take(8192 * 2);
  _Float16* ph_r3 = (_Float16*)take(8192 * 2);
  _Float16* pl_r3 = (_Float16*)take(8192 * 2);

  // CSR reservation counters must start at 0
  hipMemsetAsync(gcur, 0, (size_t)BUCKETS * 4, stream);

  prep_k<<<EBLKS + 32 + 3125, 256, 0, stream>>>(
      src, dst, gcur, binned, x, xh, Wl1, Wr1, Wl2, Wr2, Wl3, Wr3, ph_l1, pl_l1,
      ph_r1, pl_r1, ph_c2, pl_c2, ph_l3, pl_l3, ph_r3, pl_r3);
  bucket_fill_k<<<BUCKETS, 256, 0, stream>>>(binned, gcur, offs, deg, csr);

  // layer 1 aggregation, XCD-local slices: mh1 = mean(x)  (4 slices x 2 XCD copies)
  agg_sliced_k<4, false, false><<<8 * 782, 256, 0, stream>>>(
      xh, mh1, offs, deg, csr, nullptr, nullptr);

  // h1 = mh1@Wl1^T + x@Wr1^T + b1; [P|R] = h1@[Wl2;Wr2]^T (fused, h1 in LDS)
  megagemm_k<<<3125, 256, 0, stream>>>(mh1, xh, ph_l1, pl_l1, ph_r1, pl_r1, b1,
                                       ph_c2, pl_c2, Psl, Rh);

  // h2 = mean(P) + b2 + R  (sliced in, sliced out; 2 slices x 4 XCD copies)
  agg_sliced_k<2, true, true><<<8 * 391, 256, 0, stream>>>(
      Psl, h2sl, offs, deg, csr, b2, Rh);

  // mh3 = mean(h2)
  agg_sliced_k<2, false, false><<<8 * 391, 256, 0, stream>>>(
      h2sl, mh3, offs, deg, csr, nullptr, nullptr);

  // out = mh3@Wl3^T + h2@Wr3^T + b3 (fp32)
  gemm3_k<<<1564, 256, 0, stream>>>(mh3, h2sl, ph_l3, pl_l3, ph_r3, pl_r3, b3, out);
}